// Round 2
// baseline (178.803 us; speedup 1.0000x reference)
//
#include <hip/hip_runtime.h>

#define NPTS   6144
#define DIM    32
#define NB     2
#define NCELL  1000          // 10x10x10, cell edge = 0.03 = radius
#define CSTRIDE 1024
#define R2     0.0009f
#define NWAVES 4
#define BLOCK  (NWAVES * 64)
#define LEAFBIT 8192

__device__ __forceinline__ int cellof(float x) {
    int c = (int)(x * (10.0f / 0.3f));
    return min(max(c, 0), 9);
}

// ---- ws layout (ints) ----
// cnt     : [NB][CSTRIDE]            (memset 0 each call)
// leafsum : [NB] (+2 pad)            (memset 0 each call)
// cstart  : [NB][CSTRIDE+1]  (2052 ints incl pad)
// cursor  : [NB][CSTRIDE]
// rnorm   : float [NB][NPTS]
// sorted  : float4 [NB][NPTS]  (offset 73760 B, 16B aligned)
#define WS_CNT     0
#define WS_LEAF    (NB * CSTRIDE)
#define WS_CSTART  (WS_LEAF + 4)
#define WS_CURSOR  (WS_CSTART + NB * (CSTRIDE + 1) + 2)
#define WS_RNORM   (WS_CURSOR + NB * CSTRIDE)
#define WS_SORTED  (WS_RNORM + NB * NPTS)      // 18440 ints = 73760 B (16B aligned)

// K1: per-point cell count, batch leaf sum, reciprocal embedding norm
__global__ __launch_bounds__(256)
void bin_count(const float* __restrict__ points, const float* __restrict__ emb,
               const int* __restrict__ leaf, int* __restrict__ ws)
{
    const int idx = blockIdx.x * 256 + threadIdx.x;
    if (idx >= NB * NPTS) return;
    const int b = idx / NPTS;
    const float x = points[idx * 3 + 0];
    const float y = points[idx * 3 + 1];
    const float z = points[idx * 3 + 2];
    const int cell = (cellof(z) * 10 + cellof(y)) * 10 + cellof(x);
    atomicAdd(&ws[WS_CNT + b * CSTRIDE + cell], 1);
    if (leaf[idx] > 0) atomicAdd(&ws[WS_LEAF + b], 1);

    const float4* e4 = (const float4*)(emb + (size_t)idx * DIM);
    float n2 = 0.0f;
    #pragma unroll
    for (int k = 0; k < DIM / 4; ++k) {
        const float4 v = e4[k];
        n2 += v.x * v.x + v.y * v.y + v.z * v.z + v.w * v.w;
    }
    ((float*)ws)[WS_RNORM + idx] = 1.0f / fmaxf(sqrtf(n2), 1e-8f);
}

// K2: per-batch inclusive scan of cell counts -> cstart, cursor
__global__ __launch_bounds__(1024)
void cell_scan(int* __restrict__ ws)
{
    __shared__ int sdat[1024];
    const int t = threadIdx.x;
    const int b = blockIdx.x;
    const int v = (t < NCELL) ? ws[WS_CNT + b * CSTRIDE + t] : 0;
    sdat[t] = v;
    __syncthreads();
    for (int off = 1; off < 1024; off <<= 1) {
        const int x = (t >= off) ? sdat[t - off] : 0;
        __syncthreads();
        sdat[t] += x;
        __syncthreads();
    }
    const int incl = sdat[t];
    if (t == 0) ws[WS_CSTART + b * (CSTRIDE + 1)] = 0;
    if (t < NCELL) {
        ws[WS_CSTART + b * (CSTRIDE + 1) + t + 1] = incl;
        ws[WS_CURSOR + b * CSTRIDE + t] = incl - v;   // exclusive
    }
}

// K3: scatter points into cell-sorted order; pack (x,y,z, id|leaf<<13)
__global__ __launch_bounds__(256)
void scatter(const float* __restrict__ points, const int* __restrict__ leaf,
             int* __restrict__ ws)
{
    const int idx = blockIdx.x * 256 + threadIdx.x;
    if (idx >= NB * NPTS) return;
    const int b = idx / NPTS;
    const int i = idx - b * NPTS;
    const float x = points[idx * 3 + 0];
    const float y = points[idx * 3 + 1];
    const float z = points[idx * 3 + 2];
    const int cell = (cellof(z) * 10 + cellof(y)) * 10 + cellof(x);
    const int pos = atomicAdd(&ws[WS_CURSOR + b * CSTRIDE + cell], 1);
    float4* sorted = (float4*)(ws + WS_SORTED);
    const float w = (float)(i + (leaf[idx] > 0 ? LEAFBIT : 0));
    sorted[b * NPTS + pos] = make_float4(x, y, z, w);
}

// K4: wave per point; scan 9 contiguous runs of the 27-cell neighborhood
__global__ __launch_bounds__(BLOCK)
void refine(const float* __restrict__ emb,
            const float* __restrict__ W1, const float* __restrict__ b1,
            const float* __restrict__ W2, const float* __restrict__ b2,
            const int* __restrict__ ws, float* __restrict__ out)
{
    __shared__ __align__(16) float s_ei[NWAVES][DIM];
    __shared__ float s_ssum[NWAVES][DIM];
    __shared__ float s_h[NWAVES][DIM];
    __shared__ int   s_csim[NWAVES];

    const int tid  = threadIdx.x;
    const int wid  = tid >> 6;
    const int lane = tid & 63;
    const int s    = blockIdx.x * NWAVES + wid;
    const int b    = s / NPTS;
    const int slot = s - b * NPTS;

    const float4* srt   = (const float4*)(ws + WS_SORTED) + (size_t)b * NPTS;
    const float*  rn    = (const float*)ws + WS_RNORM + (size_t)b * NPTS;
    const int*    cst   = ws + WS_CSTART + b * (CSTRIDE + 1);
    const float*  embB  = emb + (size_t)b * NPTS * DIM;

    const float4 P  = srt[slot];                 // same addr all lanes
    const int    iw = (int)P.w;
    const int    io = iw & (LEAFBIT - 1);
    const bool   li = (iw & LEAFBIT) != 0;

    if (lane < DIM) {
        s_ei[wid][lane]   = embB[(size_t)io * DIM + lane];
        s_ssum[wid][lane] = 0.0f;
    }
    if (lane == 0) s_csim[wid] = 0;

    const float rni = rn[io];
    const int cx = cellof(P.x), cy = cellof(P.y), cz = cellof(P.z);

    int cnt_nb = 0;
    #pragma unroll
    for (int dz = -1; dz <= 1; ++dz) {
        const int z = cz + dz;
        if ((unsigned)z > 9u) continue;
        #pragma unroll
        for (int dy = -1; dy <= 1; ++dy) {
            const int y = cy + dy;
            if ((unsigned)y > 9u) continue;
            const int rowb = (z * 10 + y) * 10;
            const int c0   = rowb + max(cx - 1, 0);
            const int c1   = rowb + min(cx + 1, 9);
            const int beg  = cst[c0];
            const int end  = cst[c1 + 1];
            for (int base = beg; base < end; base += 64) {
                const int k  = base + lane;
                const int kk = min(k, end - 1);
                const float4 Q = srt[kk];
                const float dx = Q.x - P.x, dyy = Q.y - P.y, dzz = Q.z - P.z;
                const float d2 = dx * dx + dyy * dyy + dzz * dzz;
                const int   jw = (int)Q.w;
                const bool  nb = (k < end) && (d2 < R2) && ((jw & LEAFBIT) != 0);
                const unsigned long long m = __ballot(nb);
                cnt_nb += __popcll(m);
                if (m) {
                    if (nb) {
                        const int jo = jw & (LEAFBIT - 1);
                        const float* ej = embB + (size_t)jo * DIM;
                        float dot = 0.0f;
                        #pragma unroll
                        for (int d0 = 0; d0 < DIM; d0 += 4) {
                            const float4 a  = *(const float4*)&s_ei[wid][d0];
                            const float4 bj = *(const float4*)&ej[d0];
                            dot += a.x * bj.x + a.y * bj.y + a.z * bj.z + a.w * bj.w;
                        }
                        const float sim = dot * rni * rn[jo];
                        if (sim > 0.7f) {
                            atomicAdd(&s_csim[wid], 1);
                            #pragma unroll
                            for (int d = 0; d < DIM; ++d)
                                atomicAdd(&s_ssum[wid][d], ej[d]);
                        }
                    }
                }
            }
        }
    }

    const int  csim = s_csim[wid];
    const bool ok   = ws[WS_LEAF + b] >= 10;
    const bool cond = ok && li && (cnt_nb > 1) && (csim > 0);   // wave-uniform

    float* outp = out + ((size_t)b * NPTS + io) * DIM;
    if (lane < DIM) {
        if (!cond) {
            outp[lane] = s_ei[wid][lane];
        } else {
            s_ssum[wid][lane] = s_ssum[wid][lane] / (float)csim;
            float acc = b1[lane];
            for (int k = 0; k < DIM; ++k)
                acc = fmaf(s_ei[wid][k],   W1[k * DIM + lane], acc);
            for (int k = 0; k < DIM; ++k)
                acc = fmaf(s_ssum[wid][k], W1[(DIM + k) * DIM + lane], acc);
            s_h[wid][lane] = fmaxf(acc, 0.0f);
            float acc2 = b2[lane];
            for (int k = 0; k < DIM; ++k)
                acc2 = fmaf(s_h[wid][k], W2[k * DIM + lane], acc2);
            outp[lane] = acc2;
        }
    }
}

extern "C" void kernel_launch(void* const* d_in, const int* in_sizes, int n_in,
                              void* d_out, int out_size, void* d_ws, size_t ws_size,
                              hipStream_t stream) {
    const float* points = (const float*)d_in[0];
    const float* emb    = (const float*)d_in[1];
    const int*   leaf   = (const int*)d_in[2];
    const float* W1     = (const float*)d_in[3];
    const float* b1     = (const float*)d_in[4];
    const float* W2     = (const float*)d_in[5];
    const float* b2     = (const float*)d_in[6];
    float*       outp   = (float*)d_out;
    int*         ws     = (int*)d_ws;

    // zero cnt + leafsum (ws is re-poisoned 0xAA before every timed call)
    hipMemsetAsync(ws, 0, (size_t)(WS_LEAF + 4) * sizeof(int), stream);

    const int npt_blocks = (NB * NPTS + 255) / 256;              // 48
    bin_count<<<npt_blocks, 256, 0, stream>>>(points, emb, leaf, ws);
    cell_scan<<<NB, 1024, 0, stream>>>(ws);
    scatter<<<npt_blocks, 256, 0, stream>>>(points, leaf, ws);

    const int grid = (NB * NPTS) / NWAVES;                       // 3072
    refine<<<grid, BLOCK, 0, stream>>>(emb, W1, b1, W2, b2, ws, outp);
}

// Round 3
// 112.146 us; speedup vs baseline: 1.5944x; 1.5944x over previous
//
#include <hip/hip_runtime.h>

#define NPTS    6144
#define DIM     32
#define NB      2
#define NCELL   1000          // 10x10x10, cell edge = 0.03 = radius
#define R2      0.0009f
#define NWAVES  4
#define BLOCK   (NWAVES * 64)
#define LEAFBIT 8192
#define PPT     6             // points per thread in build_cells (6144/1024)

__device__ __forceinline__ int cellof(float x) {
    int c = (int)(x * (10.0f / 0.3f));
    return min(max(c, 0), 9);
}

// ---- ws layout (ints) ----
// leafsum : [NB]                          (written by build_cells)
// cstart  : [NB][NCELL+1]                 (2002 ints)
// sorted  : float4 [NB][NPTS]  at int-offset 2008 (byte 8032, 16B aligned)
#define WS_LEAF   0
#define WS_CSTART 4
#define WS_SORTED 2008

// K1: one block per batch. LDS histogram -> LDS scan -> LDS-cursor scatter.
// No global atomics anywhere; everything block-local.
__global__ __launch_bounds__(1024)
void build_cells(const float* __restrict__ points, const int* __restrict__ leaf,
                 int* __restrict__ ws)
{
    __shared__ int s_hist[1024];
    __shared__ int s_cursor[1024];
    __shared__ int s_leaf;

    const int t = threadIdx.x;
    const int b = blockIdx.x;

    s_hist[t] = 0;
    if (t == 0) s_leaf = 0;

    float px[PPT], py[PPT], pz[PPT];
    int   pc[PPT], pw[PPT];

    __syncthreads();

    int lc = 0;
    #pragma unroll
    for (int r = 0; r < PPT; ++r) {
        const int i  = r * 1024 + t;
        const int gi = b * NPTS + i;
        px[r] = points[gi * 3 + 0];
        py[r] = points[gi * 3 + 1];
        pz[r] = points[gi * 3 + 2];
        const int lf = leaf[gi] > 0 ? 1 : 0;
        lc += lf;
        pc[r] = (cellof(pz[r]) * 10 + cellof(py[r])) * 10 + cellof(px[r]);
        pw[r] = i + (lf ? LEAFBIT : 0);
        atomicAdd(&s_hist[pc[r]], 1);
    }
    atomicAdd(&s_leaf, lc);
    __syncthreads();

    const int v = s_hist[t];
    // Hillis-Steele inclusive scan in place
    for (int off = 1; off < 1024; off <<= 1) {
        const int x = (t >= off) ? s_hist[t - off] : 0;
        __syncthreads();
        s_hist[t] += x;
        __syncthreads();
    }
    const int incl = s_hist[t];
    s_cursor[t] = incl - v;   // exclusive start = running cursor

    if (t < NCELL) ws[WS_CSTART + b * (NCELL + 1) + t + 1] = incl;
    if (t == 0) {
        ws[WS_CSTART + b * (NCELL + 1)] = 0;
        ws[WS_LEAF + b] = s_leaf;
    }
    __syncthreads();

    float4* sorted = (float4*)(ws + WS_SORTED) + (size_t)b * NPTS;
    #pragma unroll
    for (int r = 0; r < PPT; ++r) {
        const int pos = atomicAdd(&s_cursor[pc[r]], 1);
        sorted[pos] = make_float4(px[r], py[r], pz[r], (float)pw[r]);
    }
}

// K2: wave per point; scan 9 contiguous runs of the 27-cell neighborhood.
// Norms computed inline (no rnorm array).
__global__ __launch_bounds__(BLOCK)
void refine(const float* __restrict__ emb,
            const float* __restrict__ W1, const float* __restrict__ b1,
            const float* __restrict__ W2, const float* __restrict__ b2,
            const int* __restrict__ ws, float* __restrict__ out)
{
    __shared__ __align__(16) float s_ei[NWAVES][DIM];
    __shared__ float s_ssum[NWAVES][DIM];
    __shared__ float s_h[NWAVES][DIM];
    __shared__ int   s_csim[NWAVES];

    const int tid  = threadIdx.x;
    const int wid  = tid >> 6;
    const int lane = tid & 63;
    const int s    = blockIdx.x * NWAVES + wid;
    const int b    = s / NPTS;
    const int slot = s - b * NPTS;

    const float4* srt  = (const float4*)(ws + WS_SORTED) + (size_t)b * NPTS;
    const int*    cst  = ws + WS_CSTART + b * (NCELL + 1);
    const float*  embB = emb + (size_t)b * NPTS * DIM;

    const float4 P  = srt[slot];                 // same addr all lanes
    const int    iw = (int)P.w;
    const int    io = iw & (LEAFBIT - 1);
    const bool   li = (iw & LEAFBIT) != 0;

    if (lane < DIM) {
        s_ei[wid][lane]   = embB[(size_t)io * DIM + lane];
        s_ssum[wid][lane] = 0.0f;
    }
    if (lane == 0) s_csim[wid] = 0;

    // ||e_i|| (wave-uniform; LDS broadcast reads, in-order per wave)
    float ni2 = 0.0f;
    #pragma unroll
    for (int d = 0; d < DIM; ++d) { float v = s_ei[wid][d]; ni2 += v * v; }
    const float rni = 1.0f / fmaxf(sqrtf(ni2), 1e-8f);

    const int cx = cellof(P.x), cy = cellof(P.y), cz = cellof(P.z);

    int cnt_nb = 0;
    #pragma unroll
    for (int dz = -1; dz <= 1; ++dz) {
        const int z = cz + dz;
        if ((unsigned)z > 9u) continue;
        #pragma unroll
        for (int dy = -1; dy <= 1; ++dy) {
            const int y = cy + dy;
            if ((unsigned)y > 9u) continue;
            const int rowb = (z * 10 + y) * 10;
            const int c0   = rowb + max(cx - 1, 0);
            const int c1   = rowb + min(cx + 1, 9);
            const int beg  = cst[c0];
            const int end  = cst[c1 + 1];
            for (int base = beg; base < end; base += 64) {
                const int k  = base + lane;
                const int kk = min(k, end - 1);
                const float4 Q = srt[kk];
                const float dx = Q.x - P.x, dyy = Q.y - P.y, dzz = Q.z - P.z;
                const float d2 = dx * dx + dyy * dyy + dzz * dzz;
                const int   jw = (int)Q.w;
                const bool  nb = (k < end) && (d2 < R2) && ((jw & LEAFBIT) != 0);
                const unsigned long long m = __ballot(nb);
                cnt_nb += __popcll(m);
                if (m) {
                    if (nb) {                       // divergent: rare
                        const int jo = jw & (LEAFBIT - 1);
                        const float* ej = embB + (size_t)jo * DIM;
                        float dot = 0.0f, nj2 = 0.0f;
                        #pragma unroll
                        for (int d0 = 0; d0 < DIM; d0 += 4) {
                            const float4 a  = *(const float4*)&s_ei[wid][d0];
                            const float4 bj = *(const float4*)&ej[d0];
                            dot += a.x * bj.x + a.y * bj.y + a.z * bj.z + a.w * bj.w;
                            nj2 += bj.x * bj.x + bj.y * bj.y + bj.z * bj.z + bj.w * bj.w;
                        }
                        const float rnj = 1.0f / fmaxf(sqrtf(nj2), 1e-8f);
                        const float sim = dot * rni * rnj;
                        if (sim > 0.7f) {
                            atomicAdd(&s_csim[wid], 1);
                            #pragma unroll
                            for (int d = 0; d < DIM; ++d)
                                atomicAdd(&s_ssum[wid][d], ej[d]);
                        }
                    }
                }
            }
        }
    }

    const int  csim = s_csim[wid];
    const bool ok   = ws[WS_LEAF + b] >= 10;
    const bool cond = ok && li && (cnt_nb > 1) && (csim > 0);   // wave-uniform

    float* outp = out + ((size_t)b * NPTS + io) * DIM;
    if (lane < DIM) {
        if (!cond) {
            outp[lane] = s_ei[wid][lane];
        } else {
            s_ssum[wid][lane] = s_ssum[wid][lane] / (float)csim;
            float acc = b1[lane];
            for (int k = 0; k < DIM; ++k)
                acc = fmaf(s_ei[wid][k],   W1[k * DIM + lane], acc);
            for (int k = 0; k < DIM; ++k)
                acc = fmaf(s_ssum[wid][k], W1[(DIM + k) * DIM + lane], acc);
            s_h[wid][lane] = fmaxf(acc, 0.0f);
            float acc2 = b2[lane];
            for (int k = 0; k < DIM; ++k)
                acc2 = fmaf(s_h[wid][k], W2[k * DIM + lane], acc2);
            outp[lane] = acc2;
        }
    }
}

extern "C" void kernel_launch(void* const* d_in, const int* in_sizes, int n_in,
                              void* d_out, int out_size, void* d_ws, size_t ws_size,
                              hipStream_t stream) {
    const float* points = (const float*)d_in[0];
    const float* emb    = (const float*)d_in[1];
    const int*   leaf   = (const int*)d_in[2];
    const float* W1     = (const float*)d_in[3];
    const float* b1     = (const float*)d_in[4];
    const float* W2     = (const float*)d_in[5];
    const float* b2     = (const float*)d_in[6];
    float*       outp   = (float*)d_out;
    int*         ws     = (int*)d_ws;

    build_cells<<<NB, 1024, 0, stream>>>(points, leaf, ws);

    const int grid = (NB * NPTS) / NWAVES;                       // 3072
    refine<<<grid, BLOCK, 0, stream>>>(emb, W1, b1, W2, b2, ws, outp);
}

// Round 4
// 91.197 us; speedup vs baseline: 1.9606x; 1.2297x over previous
//
#include <hip/hip_runtime.h>

#define NPTS    6144
#define DIM     32
#define NB      2
#define NCELL   1000          // 10x10x10, cell edge = 0.03 = radius
#define R2      0.0009f
#define NWAVES  4
#define BLOCK   (NWAVES * 64)
#define LEAFBIT 8192
#define PPT     6             // points per thread in build_cells (6144/1024)
#define NBCAP   128           // max neighbors kept per point (obs ~13, max ~50)

__device__ __forceinline__ int cellof(float x) {
    int c = (int)(x * (10.0f / 0.3f));
    return min(max(c, 0), 9);
}

// ---- ws layout (ints) ----
// leafsum : [NB]
// cstart  : [NB][NCELL+1]
// sorted  : float4 [NB][NPTS] at int-offset 2008 (byte 8032, 16B aligned)
#define WS_LEAF   0
#define WS_CSTART 4
#define WS_SORTED 2008

// K1: one block per batch. LDS histogram -> shfl-based scan (5 barriers) ->
// LDS-cursor scatter. No global atomics.
__global__ __launch_bounds__(1024)
void build_cells(const float* __restrict__ points, const int* __restrict__ leaf,
                 int* __restrict__ ws)
{
    __shared__ int s_hist[1024];
    __shared__ int s_cursor[1024];
    __shared__ int s_wsum[16];
    __shared__ int s_leaf;

    const int t = threadIdx.x;
    const int b = blockIdx.x;
    const int w = t >> 6, lane = t & 63;

    s_hist[t] = 0;
    if (t == 0) s_leaf = 0;

    float px[PPT], py[PPT], pz[PPT];
    int   pc[PPT], pw[PPT];

    __syncthreads();

    int lc = 0;
    #pragma unroll
    for (int r = 0; r < PPT; ++r) {
        const int i  = r * 1024 + t;
        const int gi = b * NPTS + i;
        px[r] = points[gi * 3 + 0];
        py[r] = points[gi * 3 + 1];
        pz[r] = points[gi * 3 + 2];
        const int lf = leaf[gi] > 0 ? 1 : 0;
        lc += lf;
        pc[r] = (cellof(pz[r]) * 10 + cellof(py[r])) * 10 + cellof(px[r]);
        pw[r] = i + (lf ? LEAFBIT : 0);
        atomicAdd(&s_hist[pc[r]], 1);
    }
    // wave-reduce leaf count, one LDS atomic per wave
    #pragma unroll
    for (int off = 32; off > 0; off >>= 1) lc += __shfl_down(lc, off);
    if (lane == 0) atomicAdd(&s_leaf, lc);
    __syncthreads();

    const int v = s_hist[t];
    // per-wave inclusive scan via shfl
    int x = v;
    #pragma unroll
    for (int off = 1; off < 64; off <<= 1) {
        const int y = __shfl_up(x, off);
        if (lane >= off) x += y;
    }
    if (lane == 63) s_wsum[w] = x;
    __syncthreads();
    if (t < 16) {   // scan the 16 wave totals (lanes 0..15 of wave 0)
        int wv = s_wsum[t];
        #pragma unroll
        for (int off = 1; off < 16; off <<= 1) {
            const int y = __shfl_up(wv, off);
            if (t >= off) wv += y;
        }
        s_wsum[t] = wv;
    }
    __syncthreads();
    const int incl = x + (w > 0 ? s_wsum[w - 1] : 0);
    s_cursor[t] = incl - v;   // exclusive start = running cursor

    if (t < NCELL) ws[WS_CSTART + b * (NCELL + 1) + t + 1] = incl;
    if (t == 0) {
        ws[WS_CSTART + b * (NCELL + 1)] = 0;
        ws[WS_LEAF + b] = s_leaf;
    }
    __syncthreads();

    float4* sorted = (float4*)(ws + WS_SORTED) + (size_t)b * NPTS;
    #pragma unroll
    for (int r = 0; r < PPT; ++r) {
        const int pos = atomicAdd(&s_cursor[pc[r]], 1);
        sorted[pos] = make_float4(px[r], py[r], pz[r], (float)pw[r]);
    }
}

// K2: wave per point. Phase A: virtually-concatenated 9-run candidate list,
// full-width passes, compact nb indices into LDS. Phase B: one lane per hit
// computes the 32-d cosine; survivors accumulate via LDS atomics.
__global__ __launch_bounds__(BLOCK)
void refine(const float* __restrict__ emb,
            const float* __restrict__ W1, const float* __restrict__ b1,
            const float* __restrict__ W2, const float* __restrict__ b2,
            const int* __restrict__ ws, float* __restrict__ out)
{
    __shared__ __align__(16) float s_ei[NWAVES][DIM];
    __shared__ float s_ssum[NWAVES][DIM];
    __shared__ float s_h[NWAVES][DIM];
    __shared__ int   s_nb[NWAVES][NBCAP];

    const int tid  = threadIdx.x;
    const int wid  = tid >> 6;
    const int lane = tid & 63;
    const int s    = blockIdx.x * NWAVES + wid;
    const int b    = s / NPTS;
    const int slot = s - b * NPTS;

    const float4* srt  = (const float4*)(ws + WS_SORTED) + (size_t)b * NPTS;
    const int*    cst  = ws + WS_CSTART + b * (NCELL + 1);
    const float*  embB = emb + (size_t)b * NPTS * DIM;

    const float4 P  = srt[slot];
    const int    iw = (int)P.w;
    const int    io = iw & (LEAFBIT - 1);
    const bool   li = (iw & LEAFBIT) != 0;

    if (lane < DIM) {
        s_ei[wid][lane]   = embB[(size_t)io * DIM + lane];
        s_ssum[wid][lane] = 0.0f;
    }

    float ni2 = 0.0f;
    #pragma unroll
    for (int d = 0; d < DIM; ++d) { const float v = s_ei[wid][d]; ni2 += v * v; }
    const float rni = 1.0f / fmaxf(sqrtf(ni2), 1e-8f);

    const int cx = cellof(P.x), cy = cellof(P.y), cz = cellof(P.z);

    // lanes 0..8 fetch row-run bounds (dz = r/3-1, dy = r%3-1)
    int begv = 0, lenv = 0;
    if (lane < 9) {
        const int z = cz + lane / 3 - 1;
        const int y = cy + lane % 3 - 1;
        if ((unsigned)z <= 9u && (unsigned)y <= 9u) {
            const int rowb = (z * 10 + y) * 10;
            const int c0   = rowb + max(cx - 1, 0);
            const int c1   = rowb + min(cx + 1, 9);
            begv = cst[c0];
            lenv = cst[c1 + 1] - begv;
        }
    }
    const int rb0 = __shfl(begv, 0), rb1 = __shfl(begv, 1), rb2 = __shfl(begv, 2);
    const int rb3 = __shfl(begv, 3), rb4 = __shfl(begv, 4), rb5 = __shfl(begv, 5);
    const int rb6 = __shfl(begv, 6), rb7 = __shfl(begv, 7), rb8 = __shfl(begv, 8);
    const int ln0 = __shfl(lenv, 0), ln1 = __shfl(lenv, 1), ln2 = __shfl(lenv, 2);
    const int ln3 = __shfl(lenv, 3), ln4 = __shfl(lenv, 4), ln5 = __shfl(lenv, 5);
    const int ln6 = __shfl(lenv, 6), ln7 = __shfl(lenv, 7), ln8 = __shfl(lenv, 8);
    const int pf1 = ln0,       pf2 = pf1 + ln1, pf3 = pf2 + ln2;
    const int pf4 = pf3 + ln3, pf5 = pf4 + ln4, pf6 = pf5 + ln5;
    const int pf7 = pf6 + ln6, pf8 = pf7 + ln7, pf9 = pf8 + ln8;   // total

    // ---- Phase A: scan candidates, compact nb hits into s_nb ----
    int nbcnt = 0;
    for (int base = 0; base < pf9; base += 64) {
        const int g = base + lane;
        int j = 0;                       // run-select, descending overwrite
        if (g < pf9) j = rb8 + g - pf8;
        if (g < pf8) j = rb7 + g - pf7;
        if (g < pf7) j = rb6 + g - pf6;
        if (g < pf6) j = rb5 + g - pf5;
        if (g < pf5) j = rb4 + g - pf4;
        if (g < pf4) j = rb3 + g - pf3;
        if (g < pf3) j = rb2 + g - pf2;
        if (g < pf2) j = rb1 + g - pf1;
        if (g < pf1) j = rb0 + g;
        const float4 Q  = srt[j];
        const float dx = Q.x - P.x, dy = Q.y - P.y, dz = Q.z - P.z;
        const float d2 = dx * dx + dy * dy + dz * dz;
        const int   jw = (int)Q.w;
        const bool  nb = (g < pf9) && (d2 < R2) && ((jw & LEAFBIT) != 0);
        const unsigned long long m = __ballot(nb);
        if (nb) {
            const int pos = nbcnt + __popcll(m & ((1ull << lane) - 1ull));
            if (pos < NBCAP) s_nb[wid][pos] = jw & (LEAFBIT - 1);
        }
        nbcnt += __popcll(m);
    }
    const int cnt_nb = nbcnt;

    // ---- Phase B: one lane per hit ----
    int csim = 0;
    const int nh = min(cnt_nb, NBCAP);
    for (int h0 = 0; h0 < nh; h0 += 64) {
        const int h = h0 + lane;
        bool surv = false;
        float ejr[DIM];
        if (h < nh) {
            const int jo = s_nb[wid][h];
            const float4* ej4 = (const float4*)(embB + (size_t)jo * DIM);
            #pragma unroll
            for (int k = 0; k < DIM / 4; ++k) {
                const float4 v = ej4[k];
                ejr[4 * k + 0] = v.x; ejr[4 * k + 1] = v.y;
                ejr[4 * k + 2] = v.z; ejr[4 * k + 3] = v.w;
            }
            float dot = 0.0f, nj2 = 0.0f;
            #pragma unroll
            for (int d = 0; d < DIM; ++d) {
                dot += s_ei[wid][d] * ejr[d];
                nj2 += ejr[d] * ejr[d];
            }
            const float rnj = 1.0f / fmaxf(sqrtf(nj2), 1e-8f);
            surv = (dot * rni * rnj) > 0.7f;
        }
        csim += __popcll(__ballot(surv));
        if (surv) {
            #pragma unroll
            for (int d = 0; d < DIM; ++d)
                atomicAdd(&s_ssum[wid][d], ejr[d]);
        }
    }

    const bool ok   = ws[WS_LEAF + b] >= 10;
    const bool cond = ok && li && (cnt_nb > 1) && (csim > 0);   // wave-uniform

    float* outp = out + ((size_t)b * NPTS + io) * DIM;
    if (lane < DIM) {
        if (!cond) {
            outp[lane] = s_ei[wid][lane];
        } else {
            s_ssum[wid][lane] = s_ssum[wid][lane] / (float)csim;
            float acc = b1[lane];
            for (int k = 0; k < DIM; ++k)
                acc = fmaf(s_ei[wid][k],   W1[k * DIM + lane], acc);
            for (int k = 0; k < DIM; ++k)
                acc = fmaf(s_ssum[wid][k], W1[(DIM + k) * DIM + lane], acc);
            s_h[wid][lane] = fmaxf(acc, 0.0f);
            float acc2 = b2[lane];
            for (int k = 0; k < DIM; ++k)
                acc2 = fmaf(s_h[wid][k], W2[k * DIM + lane], acc2);
            outp[lane] = acc2;
        }
    }
}

extern "C" void kernel_launch(void* const* d_in, const int* in_sizes, int n_in,
                              void* d_out, int out_size, void* d_ws, size_t ws_size,
                              hipStream_t stream) {
    const float* points = (const float*)d_in[0];
    const float* emb    = (const float*)d_in[1];
    const int*   leaf   = (const int*)d_in[2];
    const float* W1     = (const float*)d_in[3];
    const float* b1     = (const float*)d_in[4];
    const float* W2     = (const float*)d_in[5];
    const float* b2     = (const float*)d_in[6];
    float*       outp   = (float*)d_out;
    int*         ws     = (int*)d_ws;

    build_cells<<<NB, 1024, 0, stream>>>(points, leaf, ws);

    const int grid = (NB * NPTS) / NWAVES;                       // 3072
    refine<<<grid, BLOCK, 0, stream>>>(emb, W1, b1, W2, b2, ws, outp);
}